// Round 3
// baseline (26.634 us; speedup 1.0000x reference)
//
#include <hip/hip_runtime.h>
#include <math.h>

// Problem constants (fixed by setup_inputs): h [8,4096,512] f32, patch_ids [8,4096] i32 sorted,
// P=1024, k=4. Output [8,1024,512] f32.
#define BS   8
#define SEQ  4096
#define DIM  512
#define NP   1024
#define KTOP 4
#define NEGINF_C (-1.0e9f)

typedef float f32x4 __attribute__((ext_vector_type(4)));

// ---------------------------------------------------------------------------
// Kernel A: segment boundaries. starts[b*(NP+1)+p] = first token index t with
// ids[t] >= p (lower_bound). starts[b][NP] = SEQ. Exploits sortedness.
// ---------------------------------------------------------------------------
__global__ __launch_bounds__(256) void boundaries_kernel(const int* __restrict__ pid,
                                                         int* __restrict__ starts) {
    const int gt = blockIdx.x * 256 + threadIdx.x;   // [0, BS*SEQ)
    const int b  = gt / SEQ;
    const int t  = gt - b * SEQ;
    const int* ids = pid + b * SEQ;
    int* st = starts + b * (NP + 1);

    const int cur  = ids[t];
    const int prev = (t > 0) ? ids[t - 1] : -1;
    for (int p = prev + 1; p <= cur; ++p) st[p] = t;
    if (t == SEQ - 1) {
        for (int p = cur + 1; p <= NP; ++p) st[p] = SEQ;
    }
}

// ---------------------------------------------------------------------------
// Branchless distinct-insert into descending 4-list.
// Reference semantics: each iteration takes the max and knocks out ALL ties,
// so collected values = distinct values in descending order. Maintaining the
// "top-4 distinct of the multiset seen so far" is order-independent, and
// re-inserting any already-seen value is a no-op (dup-dropped if in list,
// falls off the end if below m3). This makes clamped chunk loads legal.
// ---------------------------------------------------------------------------
__device__ __forceinline__ void ins4(float v, float& m0, float& m1, float& m2, float& m3) {
    const bool dup = (v == m0) | (v == m1) | (v == m2) | (v == m3);
    v = dup ? -INFINITY : v;   // -inf never displaces anything
    float a;
    a = fmaxf(m0, v); v = fminf(m0, v); m0 = a;
    a = fmaxf(m1, v); v = fminf(m1, v); m1 = a;
    a = fmaxf(m2, v); v = fminf(m2, v); m2 = a;
    m3 = fmaxf(m3, v);
}

// ---------------------------------------------------------------------------
// Kernel B: one block per (b, p). 128 threads x f32x4 = 512 dims.
// Tokens processed in chunks of 4 with clamped indices -> 4 loads in flight.
// ---------------------------------------------------------------------------
__global__ __launch_bounds__(128) void topk_pool_kernel(const float* __restrict__ h,
                                                        const int* __restrict__ starts,
                                                        float* __restrict__ out) {
    const int bp = blockIdx.x;            // b*NP + p
    const int b  = bp >> 10;              // / NP
    const int p  = bp & (NP - 1);
    const int tid = threadIdx.x;

    const int* st   = starts + b * (NP + 1);
    const int start = st[p];
    const int end   = st[p + 1];
    const int cnt   = end - start;

    f32x4* outv = (f32x4*)(out + ((size_t)b * NP + p) * DIM);

    if (cnt == 0) {                       // empty patch -> all-zero row
        __builtin_nontemporal_store((f32x4){0.f, 0.f, 0.f, 0.f}, &outv[tid]);
        return;
    }

    const f32x4* hb = (const f32x4*)(h + (size_t)b * SEQ * DIM);

    // 4 descending top-4-distinct lists, one per owned dim. Static indexing only.
    float m[4][4];
    #pragma unroll
    for (int d = 0; d < 4; ++d)
        #pragma unroll
        for (int i = 0; i < 4; ++i) m[d][i] = -INFINITY;

    const int last = end - 1;
    for (int t = start; t < end; t += 4) {
        const int t0 = t;
        const int t1 = (t + 1 < end) ? t + 1 : last;
        const int t2 = (t + 2 < end) ? t + 2 : last;
        const int t3 = (t + 3 < end) ? t + 3 : last;
        const f32x4 v0 = hb[(size_t)t0 * (DIM / 4) + tid];
        const f32x4 v1 = hb[(size_t)t1 * (DIM / 4) + tid];
        const f32x4 v2 = hb[(size_t)t2 * (DIM / 4) + tid];
        const f32x4 v3 = hb[(size_t)t3 * (DIM / 4) + tid];
        ins4(v0.x, m[0][0], m[0][1], m[0][2], m[0][3]);
        ins4(v0.y, m[1][0], m[1][1], m[1][2], m[1][3]);
        ins4(v0.z, m[2][0], m[2][1], m[2][2], m[2][3]);
        ins4(v0.w, m[3][0], m[3][1], m[3][2], m[3][3]);
        ins4(v1.x, m[0][0], m[0][1], m[0][2], m[0][3]);
        ins4(v1.y, m[1][0], m[1][1], m[1][2], m[1][3]);
        ins4(v1.z, m[2][0], m[2][1], m[2][2], m[2][3]);
        ins4(v1.w, m[3][0], m[3][1], m[3][2], m[3][3]);
        ins4(v2.x, m[0][0], m[0][1], m[0][2], m[0][3]);
        ins4(v2.y, m[1][0], m[1][1], m[1][2], m[1][3]);
        ins4(v2.z, m[2][0], m[2][1], m[2][2], m[2][3]);
        ins4(v2.w, m[3][0], m[3][1], m[3][2], m[3][3]);
        ins4(v3.x, m[0][0], m[0][1], m[0][2], m[0][3]);
        ins4(v3.y, m[1][0], m[1][1], m[1][2], m[1][3]);
        ins4(v3.z, m[2][0], m[2][1], m[2][2], m[2][3]);
        ins4(v3.w, m[3][0], m[3][1], m[3][2], m[3][3]);
    }

    const int n = (cnt < KTOP) ? cnt : KTOP;
    const float nf = (float)n;
    float s[4];
    #pragma unroll
    for (int d = 0; d < 4; ++d) {
        float acc = 0.0f;
        #pragma unroll
        for (int i = 0; i < KTOP; ++i) {
            if (i < n) {
                // fewer than n distinct values -> reference averages NEG_INF pads
                acc += (m[d][i] == -INFINITY) ? NEGINF_C : m[d][i];
            }
        }
        s[d] = acc / nf;
    }
    __builtin_nontemporal_store((f32x4){s[0], s[1], s[2], s[3]}, &outv[tid]);
}

// ---------------------------------------------------------------------------
extern "C" void kernel_launch(void* const* d_in, const int* in_sizes, int n_in,
                              void* d_out, int out_size, void* d_ws, size_t ws_size,
                              hipStream_t stream) {
    const float* h   = (const float*)d_in[0];
    const int*   pid = (const int*)d_in[1];
    float*       out = (float*)d_out;
    int*         starts = (int*)d_ws;     // BS*(NP+1)*4 = 32.8 KB

    boundaries_kernel<<<dim3((BS * SEQ) / 256), dim3(256), 0, stream>>>(pid, starts);
    topk_pool_kernel<<<dim3(BS * NP), dim3(128), 0, stream>>>(h, starts, out);
}

// Round 4
// 26.515 us; speedup vs baseline: 1.0045x; 1.0045x over previous
//
#include <hip/hip_runtime.h>
#include <math.h>

// Problem constants (fixed by setup_inputs): h [8,4096,512] f32, patch_ids [8,4096] i32 sorted,
// P=1024, k=4. Output [8,1024,512] f32.
#define BS   8
#define SEQ  4096
#define DIM  512
#define NP   1024
#define KTOP 4
#define NEGINF_C (-1.0e9f)

typedef float f32x4 __attribute__((ext_vector_type(4)));

// ---------------------------------------------------------------------------
// Branchless distinct-insert into descending 4-list.
// Reference semantics: each iteration takes the max and knocks out ALL ties,
// so collected values = distinct values in descending order. Maintaining the
// "top-4 distinct of the multiset seen so far" is order-independent, and
// re-inserting any already-seen value is a no-op (dup-dropped if in list,
// falls off the end if below m3). This makes clamped chunk loads legal.
// ---------------------------------------------------------------------------
__device__ __forceinline__ void ins4(float v, float& m0, float& m1, float& m2, float& m3) {
    const bool dup = (v == m0) | (v == m1) | (v == m2) | (v == m3);
    v = dup ? -INFINITY : v;   // -inf never displaces anything
    float a;
    a = fmaxf(m0, v); v = fminf(m0, v); m0 = a;
    a = fmaxf(m1, v); v = fminf(m1, v); m1 = a;
    a = fmaxf(m2, v); v = fminf(m2, v); m2 = a;
    m3 = fmaxf(m3, v);
}

// ---------------------------------------------------------------------------
// Fused kernel: one block per (b, p). 128 threads x f32x4 = 512 dims.
// Boundaries via in-wave binary search over sorted ids (12 steps, L1/L2-hot):
// every lane searches target = p + (lane&1); shfl broadcasts within the wave.
// No second kernel, no starts[] round-trip, no inter-kernel graph drain.
// ---------------------------------------------------------------------------
__global__ __launch_bounds__(128) void topk_pool_fused_kernel(const float* __restrict__ h,
                                                              const int* __restrict__ pid,
                                                              float* __restrict__ out) {
    const int bp = blockIdx.x;            // b*NP + p
    const int b  = bp >> 10;              // / NP
    const int p  = bp & (NP - 1);
    const int tid = threadIdx.x;

    // --- lower_bound(ids, p + (tid&1)) over sorted ids[b][0..SEQ) ---
    const int* ids = pid + b * SEQ;
    const int target = p + (tid & 1);
    int lo = 0, hi = SEQ;
    #pragma unroll
    for (int s = 0; s < 12; ++s) {        // 2^12 == SEQ, exact
        const int mid = (lo + hi) >> 1;
        const bool go = ids[mid] < target;
        lo = go ? mid + 1 : lo;
        hi = go ? hi : mid;
    }
    const int start = __shfl(lo, 0);      // lower_bound(p)
    const int end   = __shfl(lo, 1);      // lower_bound(p+1)
    const int cnt   = end - start;

    f32x4* outv = (f32x4*)(out + ((size_t)b * NP + p) * DIM);

    if (cnt == 0) {                       // empty patch -> all-zero row
        __builtin_nontemporal_store((f32x4){0.f, 0.f, 0.f, 0.f}, &outv[tid]);
        return;
    }

    const f32x4* hb = (const f32x4*)(h + (size_t)b * SEQ * DIM);

    // 4 descending top-4-distinct lists, one per owned dim. Static indexing only.
    float m[4][4];
    #pragma unroll
    for (int d = 0; d < 4; ++d)
        #pragma unroll
        for (int i = 0; i < 4; ++i) m[d][i] = -INFINITY;

    const int last = end - 1;
    for (int t = start; t < end; t += 4) {
        const int t0 = t;
        const int t1 = (t + 1 < end) ? t + 1 : last;
        const int t2 = (t + 2 < end) ? t + 2 : last;
        const int t3 = (t + 3 < end) ? t + 3 : last;
        const f32x4 v0 = hb[(size_t)t0 * (DIM / 4) + tid];
        const f32x4 v1 = hb[(size_t)t1 * (DIM / 4) + tid];
        const f32x4 v2 = hb[(size_t)t2 * (DIM / 4) + tid];
        const f32x4 v3 = hb[(size_t)t3 * (DIM / 4) + tid];
        ins4(v0.x, m[0][0], m[0][1], m[0][2], m[0][3]);
        ins4(v0.y, m[1][0], m[1][1], m[1][2], m[1][3]);
        ins4(v0.z, m[2][0], m[2][1], m[2][2], m[2][3]);
        ins4(v0.w, m[3][0], m[3][1], m[3][2], m[3][3]);
        ins4(v1.x, m[0][0], m[0][1], m[0][2], m[0][3]);
        ins4(v1.y, m[1][0], m[1][1], m[1][2], m[1][3]);
        ins4(v1.z, m[2][0], m[2][1], m[2][2], m[2][3]);
        ins4(v1.w, m[3][0], m[3][1], m[3][2], m[3][3]);
        ins4(v2.x, m[0][0], m[0][1], m[0][2], m[0][3]);
        ins4(v2.y, m[1][0], m[1][1], m[1][2], m[1][3]);
        ins4(v2.z, m[2][0], m[2][1], m[2][2], m[2][3]);
        ins4(v2.w, m[3][0], m[3][1], m[3][2], m[3][3]);
        ins4(v3.x, m[0][0], m[0][1], m[0][2], m[0][3]);
        ins4(v3.y, m[1][0], m[1][1], m[1][2], m[1][3]);
        ins4(v3.z, m[2][0], m[2][1], m[2][2], m[2][3]);
        ins4(v3.w, m[3][0], m[3][1], m[3][2], m[3][3]);
    }

    const int n = (cnt < KTOP) ? cnt : KTOP;
    const float nf = (float)n;
    float s[4];
    #pragma unroll
    for (int d = 0; d < 4; ++d) {
        float acc = 0.0f;
        #pragma unroll
        for (int i = 0; i < KTOP; ++i) {
            if (i < n) {
                // fewer than n distinct values -> reference averages NEG_INF pads
                acc += (m[d][i] == -INFINITY) ? NEGINF_C : m[d][i];
            }
        }
        s[d] = acc / nf;
    }
    __builtin_nontemporal_store((f32x4){s[0], s[1], s[2], s[3]}, &outv[tid]);
}

// ---------------------------------------------------------------------------
extern "C" void kernel_launch(void* const* d_in, const int* in_sizes, int n_in,
                              void* d_out, int out_size, void* d_ws, size_t ws_size,
                              hipStream_t stream) {
    const float* h   = (const float*)d_in[0];
    const int*   pid = (const int*)d_in[1];
    float*       out = (float*)d_out;
    (void)d_ws; (void)ws_size;

    topk_pool_fused_kernel<<<dim3(BS * NP), dim3(128), 0, stream>>>(h, pid, out);
}